// Round 4
// baseline (56.471 us; speedup 1.0000x reference)
//
#include <hip/hip_runtime.h>
#include <math.h>

constexpr int NB = 256;   // batch
constexpr int NS = 128;   // seq len
constexpr int NE = 256;   // embed dim
constexpr int DIN = 260;  // E + H

// ---------- fast primitives ----------
__device__ __forceinline__ float rcp_fast(float x) {
#if __has_builtin(__builtin_amdgcn_rcpf)
    return __builtin_amdgcn_rcpf(x);
#else
    return 1.0f / x;
#endif
}

#if __has_builtin(__builtin_amdgcn_mov_dpp)
#define DPP_XOR1(x) __int_as_float(__builtin_amdgcn_mov_dpp(__float_as_int(x), 0xB1, 0xF, 0xF, true))
#define DPP_XOR2(x) __int_as_float(__builtin_amdgcn_mov_dpp(__float_as_int(x), 0x4E, 0xF, 0xF, true))
#define DPP_XOR3(x) __int_as_float(__builtin_amdgcn_mov_dpp(__float_as_int(x), 0x1B, 0xF, 0xF, true))
#else
#define DPP_XOR1(x) __shfl_xor((x), 1, 64)
#define DPP_XOR2(x) __shfl_xor((x), 2, 64)
#define DPP_XOR3(x) __shfl_xor((x), 3, 64)
#endif

// Padé(3,2) tanh: err <=1.1e-6 on |z|<=0.5, <=3.2e-4 on |z|<=1. One trans op.
__device__ __forceinline__ float pade_tanh(float z) {
    float w = z * z;
    float num = z * (w + 15.0f);
    float den = fmaf(6.0f, w, 15.0f);
    return num * rcp_fast(den);
}

// Lambert continued-fraction tanh for the c-gate (|c| <= ~2.1): err ~2e-5.
__device__ __forceinline__ float tanh_cf(float y) {
    float w = y * y;
    float num = y * fmaf(fmaf(21.0f, w, 1260.0f), w, 10395.0f);
    float den = fmaf(fmaf(w + 210.0f, w, 4725.0f), w, 10395.0f);
    return num * rcp_fast(den);
}

__device__ __forceinline__ float sel4f(float v0, float v1, float v2, float v3,
                                       bool bit0, bool bit1) {
    float lo = bit0 ? v1 : v0;
    float hi = bit0 ? v3 : v2;
    return bit1 ? hi : lo;
}

// async global->LDS, 16B per lane. dst must be wave-uniform base; HW adds lane*16.
__device__ __forceinline__ void gload_lds16(const void* gsrc, void* ldst) {
    __builtin_amdgcn_global_load_lds(
        (const __attribute__((address_space(1))) void*)gsrc,
        (__attribute__((address_space(3))) void*)ldst, 16, 0, 0);
}

// ---------------- Kernel 1: x-part of all 4 gate preactivations ----------------
__global__ __launch_bounds__(256) void k_embed(
    const int* __restrict__ x, const float* __restrict__ emb,
    const float* __restrict__ Wf, const float* __restrict__ bf,
    const float* __restrict__ Wi, const float* __restrict__ bi,
    const float* __restrict__ Wu, const float* __restrict__ bu,
    const float* __restrict__ Wo, const float* __restrict__ bo,
    const float* __restrict__ thf, const float* __restrict__ thi,
    const float* __restrict__ thu, const float* __restrict__ tho,
    float* __restrict__ xpart)
{
    const int lane = threadIdx.x & 63;
    const int wave_id = blockIdx.x * 4 + (threadIdx.x >> 6);  // 0..2047

    float4 Wreg[16];
    #pragma unroll
    for (int j = 0; j < 16; ++j) {
        const float* Wgp = (j < 8) ? ((j < 4) ? Wf : Wi) : ((j < 12) ? Wu : Wo);
        Wreg[j] = *(const float4*)(Wgp + (j & 3) * DIN + lane * 4);
    }
    float biasv;
    {
        int j = lane & 15, jj = j & 3;
        const float* bp = (j < 8) ? ((j < 4) ? bf : bi) : ((j < 12) ? bu : bo);
        const float* tp = (j < 8) ? ((j < 4) ? thf : thi) : ((j < 12) ? thu : tho);
        biasv = bp[jj] + tp[jj];
    }

    const bool p0 = (lane & 1) != 0, p1 = (lane & 2) != 0,
               p2 = (lane & 4) != 0, p3 = (lane & 8) != 0;

    int row0 = wave_id * 16;
    for (int i = 0; i < 16; ++i) {
        int r = row0 + i;            // r = s*256 + b
        int b = r & 255, s = r >> 8;
        int tok = x[b * NS + s];
        float4 ev = *(const float4*)(emb + (size_t)tok * NE + lane * 4);

        float acc[16];
        #pragma unroll
        for (int j = 0; j < 16; ++j) {
            float4 wv = Wreg[j];
            acc[j] = fmaf(ev.x, wv.x, fmaf(ev.y, wv.y, fmaf(ev.z, wv.z, ev.w * wv.w)));
        }
        float t8[8];
        #pragma unroll
        for (int i2 = 0; i2 < 8; ++i2) {
            float keep = p0 ? acc[2 * i2 + 1] : acc[2 * i2];
            float send = p0 ? acc[2 * i2] : acc[2 * i2 + 1];
            t8[i2] = keep + __shfl_xor(send, 1, 64);
        }
        float t4[4];
        #pragma unroll
        for (int i2 = 0; i2 < 4; ++i2) {
            float keep = p1 ? t8[2 * i2 + 1] : t8[2 * i2];
            float send = p1 ? t8[2 * i2] : t8[2 * i2 + 1];
            t4[i2] = keep + __shfl_xor(send, 2, 64);
        }
        float t2[2];
        #pragma unroll
        for (int i2 = 0; i2 < 2; ++i2) {
            float keep = p2 ? t4[2 * i2 + 1] : t4[2 * i2];
            float send = p2 ? t4[2 * i2] : t4[2 * i2 + 1];
            t2[i2] = keep + __shfl_xor(send, 4, 64);
        }
        float keep = p3 ? t2[1] : t2[0];
        float send = p3 ? t2[0] : t2[1];
        float t1 = keep + __shfl_xor(send, 8, 64);
        t1 += __shfl_xor(t1, 16, 64);
        t1 += __shfl_xor(t1, 32, 64);

        if (lane < 16)
            xpart[(size_t)r * 16 + lane] = t1 + biasv;
    }
}

// ---------------- Kernel 2: serial LSTM recurrence, LDS-staged, vmcnt-free loop ------
// lane = gate g (also state index j); 16 batches per block (1 wave).
// xpart staged into LDS in 16-step chunks (double-buffered) via global_load_lds;
// hn routed through LDS so the in-loop vmcnt FIFO holds ONLY staging loads.
__global__ __launch_bounds__(64) void k_recur(
    const float* __restrict__ Wf, const float* __restrict__ Wi,
    const float* __restrict__ Wu, const float* __restrict__ Wo,
    const float* __restrict__ xpart, float* __restrict__ hs)
{
    __shared__ float4 xlds[2][16][64];   // 32 KB: [buf][step-in-chunk][lane]
    __shared__ float  hlds[128][64];     // 32 KB: [s][lane]  (lane = b'*4+g)

    const int lane = threadIdx.x;
    const int g = lane & 3;
    const int b0 = blockIdx.x * 16;

    // pre-permuted recurrent weights: Wp[j'][k] = W_g[j'][256 + (g^k)]
    const float* Wg = (g == 0) ? Wf : ((g == 1) ? Wi : ((g == 2) ? Wu : Wo));
    float Wp[4][4];
    #pragma unroll
    for (int j2 = 0; j2 < 4; ++j2)
        #pragma unroll
        for (int k = 0; k < 4; ++k)
            Wp[j2][k] = Wg[j2 * DIN + 256 + (g ^ k)];

    const bool bb0 = (g & 1) != 0, bb1 = (g & 2) != 0;
    const float scl = (g == 2) ? 1.0f : 0.5f;
    const float mlt = (g == 2) ? 1.0f : 0.5f;
    const float bas = (g == 2) ? 0.0f : 0.5f;

    float c = 0.0f;
    float hr0 = 0.f, hr1 = 0.f, hr2 = 0.f, hr3 = 0.f;  // hr[k] = h[g^k]

    // staging source: step s occupies 1KB at xpart_bytes + s*16384 + b0*64
    const char* xblk = (const char*)xpart + (size_t)b0 * 64 + (size_t)lane * 16;

    // prologue: stage chunks 0 and 1
    #pragma unroll
    for (int i = 0; i < 16; ++i)
        gload_lds16(xblk + (size_t)i * 16384, &xlds[0][i][0]);
    #pragma unroll
    for (int i = 0; i < 16; ++i)
        gload_lds16(xblk + (size_t)(16 + i) * 16384, &xlds[1][i][0]);
    asm volatile("s_waitcnt vmcnt(16)" ::: "memory");   // chunk 0 landed

#define QS(I) do {                                                            \
    float4 xc = xlds[bsel][I][lane];                                          \
    float m0 = fmaf(Wp[0][2], hr2, Wp[0][3] * hr3);                           \
    float v0 = fmaf(Wp[0][1], hr1, m0);                                       \
    float u0 = fmaf(Wp[0][0], hr0, xc.x);                                     \
    float a0 = u0 + v0;                                                       \
    float m1 = fmaf(Wp[1][2], hr2, Wp[1][3] * hr3);                           \
    float v1 = fmaf(Wp[1][1], hr1, m1);                                       \
    float u1 = fmaf(Wp[1][0], hr0, xc.y);                                     \
    float a1 = u1 + v1;                                                       \
    float m2 = fmaf(Wp[2][2], hr2, Wp[2][3] * hr3);                           \
    float v2 = fmaf(Wp[2][1], hr1, m2);                                       \
    float u2 = fmaf(Wp[2][0], hr0, xc.z);                                     \
    float a2 = u2 + v2;                                                       \
    float m3 = fmaf(Wp[3][2], hr2, Wp[3][3] * hr3);                           \
    float v3 = fmaf(Wp[3][1], hr1, m3);                                       \
    float u3 = fmaf(Wp[3][0], hr0, xc.w);                                     \
    float a3 = u3 + v3;                                                       \
    float c0_ = __cosf(a0), c1_ = __cosf(a1), c2_ = __cosf(a2), c3_ = __cosf(a3); \
    float tt = c2_ * c3_;                                                     \
    float q1 = c0_ * c1_;                                                     \
    float q0 = c1_ * tt;                                                      \
    float q2 = q1 * c2_;                                                      \
    float q3 = q1 * tt;                                                       \
    float A0 = fmaf(mlt, pade_tanh(scl * q0), bas);                           \
    float A1 = fmaf(mlt, pade_tanh(scl * q1), bas);                           \
    float A2 = fmaf(mlt, pade_tanh(scl * q2), bas);                           \
    float A3 = fmaf(mlt, pade_tanh(scl * q3), bas);                           \
    float r1 = DPP_XOR1(sel4f(A0, A1, A2, A3, !bb0,  bb1));                   \
    float r2 = DPP_XOR2(sel4f(A0, A1, A2, A3,  bb0, !bb1));                   \
    float r3 = DPP_XOR3(sel4f(A0, A1, A2, A3, !bb0, !bb1));                   \
    float r0 = sel4f(A0, A1, A2, A3, bb0, bb1);                               \
    float fv = sel4f(r0, r1, r2, r3,  bb0,  bb1);                             \
    float iv = sel4f(r0, r1, r2, r3, !bb0,  bb1);                             \
    float uv = sel4f(r0, r1, r2, r3,  bb0, !bb1);                             \
    float ov = sel4f(r0, r1, r2, r3, !bb0, !bb1);                             \
    c = fmaf(fv, c, iv * uv);                                                 \
    float hn = ov * tanh_cf(c);                                               \
    hlds[(cc << 4) + I][lane] = hn;                                           \
    hr0 = hn;                                                                 \
    hr1 = DPP_XOR1(hn);                                                       \
    hr2 = DPP_XOR2(hn);                                                       \
    hr3 = DPP_XOR3(hn);                                                       \
} while (0)

    for (int cc = 0; cc < 8; ++cc) {
        const int bsel = cc & 1;
        QS(0);  QS(1);  QS(2);  QS(3);
        QS(4);  QS(5);  QS(6);  QS(7);
        QS(8);  QS(9);  QS(10); QS(11);
        QS(12); QS(13); QS(14); QS(15);
        if (cc < 6) {
            // restage the buffer we just finished with chunk cc+2
            #pragma unroll
            for (int i = 0; i < 16; ++i)
                gload_lds16(xblk + (size_t)((cc + 2) * 16 + i) * 16384,
                            &xlds[bsel][i][0]);
            // only staging loads are on vmcnt: <=16 outstanding => chunk cc+1 landed
            asm volatile("s_waitcnt vmcnt(16)" ::: "memory");
        } else if (cc == 6) {
            asm volatile("s_waitcnt vmcnt(0)" ::: "memory");   // chunk 7 landed
        }
    }
#undef QS

    // epilogue: dump hlds -> hs (coalesced 16B stores)
    #pragma unroll 4
    for (int j = 0; j < 32; ++j) {
        int sp = j * 4 + (lane >> 4);
        float4 v = *(const float4*)&hlds[sp][(lane & 15) * 4];
        *(float4*)(hs + (size_t)sp * 1024 + (size_t)b0 * 4 + (lane & 15) * 4) = v;
    }
}

// ---------------- Kernel 3: logits + log_softmax ----------------
__global__ __launch_bounds__(256) void k_out(
    const float* __restrict__ hs, const float* __restrict__ Wc,
    const float* __restrict__ bc, float* __restrict__ out)
{
    int gtid = blockIdx.x * 256 + threadIdx.x;
    int r = gtid >> 3;     // r = b*S + s
    int lr = gtid & 7;
    if (r >= NB * NS) return;
    int b = r >> 7, s = r & 127;
    float4 h = *(const float4*)(hs + ((size_t)s * NB + b) * 4);
    float l[4];
    #pragma unroll
    for (int k = 0; k < 4; ++k) {
        int t = lr * 4 + k;
        float4 w = *(const float4*)(Wc + t * 4);
        l[k] = bc[t] + w.x * h.x + w.y * h.y + w.z * h.z + w.w * h.w;
    }
    float m = fmaxf(fmaxf(l[0], l[1]), fmaxf(l[2], l[3]));
    #pragma unroll
    for (int msk = 1; msk < 8; msk <<= 1)
        m = fmaxf(m, __shfl_xor(m, msk, 64));
    float sum = 0.f;
    #pragma unroll
    for (int k = 0; k < 4; ++k)
        sum += __expf(l[k] - m);
    #pragma unroll
    for (int msk = 1; msk < 8; msk <<= 1)
        sum += __shfl_xor(sum, msk, 64);
    float lse = __logf(sum);
    float4 o;
    o.x = l[0] - m - lse;
    o.y = l[1] - m - lse;
    o.z = l[2] - m - lse;
    o.w = l[3] - m - lse;
    *(float4*)(out + (size_t)r * 32 + lr * 4) = o;
}

extern "C" void kernel_launch(void* const* d_in, const int* in_sizes, int n_in,
                              void* d_out, int out_size, void* d_ws, size_t ws_size,
                              hipStream_t stream) {
    const int*   x   = (const int*)d_in[0];
    const float* emb = (const float*)d_in[1];
    const float* Wf  = (const float*)d_in[2];
    const float* bf  = (const float*)d_in[3];
    const float* Wi  = (const float*)d_in[4];
    const float* bi  = (const float*)d_in[5];
    const float* Wu  = (const float*)d_in[6];
    const float* bu  = (const float*)d_in[7];
    const float* Wo  = (const float*)d_in[8];
    const float* bo  = (const float*)d_in[9];
    const float* thf = (const float*)d_in[10];
    const float* thi = (const float*)d_in[11];
    const float* thu = (const float*)d_in[12];
    const float* tho = (const float*)d_in[13];
    const float* Wc  = (const float*)d_in[14];
    const float* bc  = (const float*)d_in[15];
    float* out = (float*)d_out;

    float* xpart = (float*)d_ws;                    // [S][B][16]  2 MB
    float* hs    = xpart + (size_t)NS * NB * 16;    // [S][B][4]   512 KB

    k_embed<<<512, 256, 0, stream>>>(x, emb, Wf, bf, Wi, bi, Wu, bu, Wo, bo,
                                     thf, thi, thu, tho, xpart);
    k_recur<<<16, 64, 0, stream>>>(Wf, Wi, Wu, Wo, xpart, hs);
    k_out<<<1024, 256, 0, stream>>>(hs, Wc, bc, out);
}

// Round 5
// 47.871 us; speedup vs baseline: 1.1797x; 1.1797x over previous
//
#include <hip/hip_runtime.h>
#include <math.h>

constexpr int NB = 256;   // batch
constexpr int NS = 128;   // seq len
constexpr int NE = 256;   // embed dim
constexpr int DIN = 260;  // E + H

// ---------- fast primitives ----------
__device__ __forceinline__ float rcp_fast(float x) {
#if __has_builtin(__builtin_amdgcn_rcpf)
    return __builtin_amdgcn_rcpf(x);
#else
    return 1.0f / x;
#endif
}

#if __has_builtin(__builtin_amdgcn_mov_dpp)
#define DPP_XOR1(x) __int_as_float(__builtin_amdgcn_mov_dpp(__float_as_int(x), 0xB1, 0xF, 0xF, true))
#define DPP_XOR2(x) __int_as_float(__builtin_amdgcn_mov_dpp(__float_as_int(x), 0x4E, 0xF, 0xF, true))
#define DPP_XOR3(x) __int_as_float(__builtin_amdgcn_mov_dpp(__float_as_int(x), 0x1B, 0xF, 0xF, true))
#else
#define DPP_XOR1(x) __shfl_xor((x), 1, 64)
#define DPP_XOR2(x) __shfl_xor((x), 2, 64)
#define DPP_XOR3(x) __shfl_xor((x), 3, 64)
#endif

// Lambert continued-fraction tanh for the c-gate (|c| <= ~2.1): err ~2e-5.
__device__ __forceinline__ float tanh_cf(float y) {
    float w = y * y;
    float num = y * fmaf(fmaf(21.0f, w, 1260.0f), w, 10395.0f);
    float den = fmaf(fmaf(w + 210.0f, w, 4725.0f), w, 10395.0f);
    return num * rcp_fast(den);
}

__device__ __forceinline__ float sel4f(float v0, float v1, float v2, float v3,
                                       bool bit0, bool bit1) {
    float lo = bit0 ? v1 : v0;
    float hi = bit0 ? v3 : v2;
    return bit1 ? hi : lo;
}

// async global->LDS, 16B per lane. dst must be wave-uniform base; HW adds lane*16.
__device__ __forceinline__ void gload_lds16(const void* gsrc, void* ldst) {
    __builtin_amdgcn_global_load_lds(
        (const __attribute__((address_space(1))) void*)gsrc,
        (__attribute__((address_space(3))) void*)ldst, 16, 0, 0);
}

// ---------------- Kernel 1: x-part of all 4 gate preactivations ----------------
// 4-deep static gather prefetch: 4 outstanding 1KB emb-row gathers per wave.
__global__ __launch_bounds__(256) void k_embed(
    const int* __restrict__ x, const float* __restrict__ emb,
    const float* __restrict__ Wf, const float* __restrict__ bf,
    const float* __restrict__ Wi, const float* __restrict__ bi,
    const float* __restrict__ Wu, const float* __restrict__ bu,
    const float* __restrict__ Wo, const float* __restrict__ bo,
    const float* __restrict__ thf, const float* __restrict__ thi,
    const float* __restrict__ thu, const float* __restrict__ tho,
    float* __restrict__ xpart)
{
    const int lane = threadIdx.x & 63;
    const int wave_id = blockIdx.x * 4 + (threadIdx.x >> 6);  // 0..2047

    float4 Wreg[16];
    #pragma unroll
    for (int j = 0; j < 16; ++j) {
        const float* Wgp = (j < 8) ? ((j < 4) ? Wf : Wi) : ((j < 12) ? Wu : Wo);
        Wreg[j] = *(const float4*)(Wgp + (j & 3) * DIN + lane * 4);
    }
    float biasv;
    {
        int j = lane & 15, jj = j & 3;
        const float* bp = (j < 8) ? ((j < 4) ? bf : bi) : ((j < 12) ? bu : bo);
        const float* tp = (j < 8) ? ((j < 4) ? thf : thi) : ((j < 12) ? thu : tho);
        biasv = bp[jj] + tp[jj];
    }

    const bool p0 = (lane & 1) != 0, p1 = (lane & 2) != 0,
               p2 = (lane & 4) != 0, p3 = (lane & 8) != 0;

    const int row0 = wave_id * 16;

#define LDE(I) (*(const float4*)(emb + \
    (size_t)x[((row0 + (I)) & 255) * NS + ((row0 + (I)) >> 8)] * NE + lane * 4))

#define PROC(I, EV) do {                                                     \
    float acc[16];                                                           \
    _Pragma("unroll")                                                        \
    for (int j = 0; j < 16; ++j) {                                           \
        float4 wv = Wreg[j];                                                 \
        acc[j] = fmaf((EV).x, wv.x, fmaf((EV).y, wv.y,                       \
                  fmaf((EV).z, wv.z, (EV).w * wv.w)));                       \
    }                                                                        \
    float t8[8];                                                             \
    _Pragma("unroll")                                                        \
    for (int i2 = 0; i2 < 8; ++i2) {                                         \
        float keep = p0 ? acc[2 * i2 + 1] : acc[2 * i2];                     \
        float send = p0 ? acc[2 * i2] : acc[2 * i2 + 1];                     \
        t8[i2] = keep + __shfl_xor(send, 1, 64);                             \
    }                                                                        \
    float t4[4];                                                             \
    _Pragma("unroll")                                                        \
    for (int i2 = 0; i2 < 4; ++i2) {                                         \
        float keep = p1 ? t8[2 * i2 + 1] : t8[2 * i2];                       \
        float send = p1 ? t8[2 * i2] : t8[2 * i2 + 1];                       \
        t4[i2] = keep + __shfl_xor(send, 2, 64);                             \
    }                                                                        \
    float t2[2];                                                             \
    _Pragma("unroll")                                                        \
    for (int i2 = 0; i2 < 2; ++i2) {                                         \
        float keep = p2 ? t4[2 * i2 + 1] : t4[2 * i2];                       \
        float send = p2 ? t4[2 * i2] : t4[2 * i2 + 1];                       \
        t2[i2] = keep + __shfl_xor(send, 4, 64);                             \
    }                                                                        \
    float keep = p3 ? t2[1] : t2[0];                                         \
    float send = p3 ? t2[0] : t2[1];                                         \
    float t1 = keep + __shfl_xor(send, 8, 64);                               \
    t1 += __shfl_xor(t1, 16, 64);                                            \
    t1 += __shfl_xor(t1, 32, 64);                                            \
    if (lane < 16)                                                           \
        xpart[(size_t)(row0 + (I)) * 16 + lane] = t1 + biasv;                \
} while (0)

    float4 ev0 = LDE(0), ev1 = LDE(1), ev2 = LDE(2), ev3 = LDE(3);
    PROC(0,  ev0); ev0 = LDE(4);
    PROC(1,  ev1); ev1 = LDE(5);
    PROC(2,  ev2); ev2 = LDE(6);
    PROC(3,  ev3); ev3 = LDE(7);
    PROC(4,  ev0); ev0 = LDE(8);
    PROC(5,  ev1); ev1 = LDE(9);
    PROC(6,  ev2); ev2 = LDE(10);
    PROC(7,  ev3); ev3 = LDE(11);
    PROC(8,  ev0); ev0 = LDE(12);
    PROC(9,  ev1); ev1 = LDE(13);
    PROC(10, ev2); ev2 = LDE(14);
    PROC(11, ev3); ev3 = LDE(15);
    PROC(12, ev0);
    PROC(13, ev1);
    PROC(14, ev2);
    PROC(15, ev3);
#undef PROC
#undef LDE
}

// ---------------- Kernel 2: serial LSTM recurrence, LDS-staged, vmcnt-free loop ------
// lane = gate g (also state index j); 16 batches per block (1 wave).
// Gate activations: odd poly in q with scl/mlt folded into per-lane coefficients
// (zero transcendental ops); only the c-tanh keeps one v_rcp.
__global__ __launch_bounds__(64) void k_recur(
    const float* __restrict__ Wf, const float* __restrict__ Wi,
    const float* __restrict__ Wu, const float* __restrict__ Wo,
    const float* __restrict__ xpart, float* __restrict__ hs)
{
    __shared__ float4 xlds[2][16][64];   // 32 KB: [buf][step-in-chunk][lane]
    __shared__ float  hlds[128][64];     // 32 KB: [s][lane]  (lane = b'*4+g)

    const int lane = threadIdx.x;
    const int g = lane & 3;
    const int b0 = blockIdx.x * 16;

    // pre-permuted recurrent weights: Wp[j'][k] = W_g[j'][256 + (g^k)]
    const float* Wg = (g == 0) ? Wf : ((g == 1) ? Wi : ((g == 2) ? Wu : Wo));
    float Wp[4][4];
    #pragma unroll
    for (int j2 = 0; j2 < 4; ++j2)
        #pragma unroll
        for (int k = 0; k < 4; ++k)
            Wp[j2][k] = Wg[j2 * DIN + 256 + (g ^ k)];

    const bool bb0 = (g & 1) != 0, bb1 = (g & 2) != 0;
    // act(q) = bas + mlt * tanh(scl*q);  tanh(z) ~= z*(P0 + P1 w + P2 w^2 + P3 w^3),
    // w=z^2, fitted on [-1,1], err <= 1e-4.  Fold mlt*scl^(2k+1) into coeffs.
    const float scl = (g == 2) ? 1.0f : 0.5f;
    const float mlt = (g == 2) ? 1.0f : 0.5f;
    const float bas = (g == 2) ? 0.0f : 0.5f;
    const float s2 = scl * scl;
    const float D0 = mlt * 0.999416f * scl;
    const float D1 = mlt * -0.326958f * scl * s2;
    const float D2 = mlt * 0.111796f * scl * s2 * s2;
    const float D3 = mlt * -0.022660f * scl * s2 * s2 * s2;

    float c = 0.0f;
    float hr0 = 0.f, hr1 = 0.f, hr2 = 0.f, hr3 = 0.f;  // hr[k] = h[g^k]

    // staging source: step s occupies 1KB at xpart_bytes + s*16384 + b0*64
    const char* xblk = (const char*)xpart + (size_t)b0 * 64 + (size_t)lane * 16;

    // prologue: stage chunks 0 and 1
    #pragma unroll
    for (int i = 0; i < 16; ++i)
        gload_lds16(xblk + (size_t)i * 16384, &xlds[0][i][0]);
    #pragma unroll
    for (int i = 0; i < 16; ++i)
        gload_lds16(xblk + (size_t)(16 + i) * 16384, &xlds[1][i][0]);
    asm volatile("s_waitcnt vmcnt(16)" ::: "memory");   // chunk 0 landed

#define GACT(Q) ({ float wq_ = (Q) * (Q);                                     \
    float pp_ = fmaf(fmaf(fmaf(D3, wq_, D2), wq_, D1), wq_, D0);              \
    fmaf((Q), pp_, bas); })

#define QS(I) do {                                                            \
    float4 xc = xlds[bsel][I][lane];                                          \
    float m0 = fmaf(Wp[0][2], hr2, Wp[0][3] * hr3);                           \
    float v0 = fmaf(Wp[0][1], hr1, m0);                                       \
    float u0 = fmaf(Wp[0][0], hr0, xc.x);                                     \
    float a0 = u0 + v0;                                                       \
    float m1 = fmaf(Wp[1][2], hr2, Wp[1][3] * hr3);                           \
    float v1 = fmaf(Wp[1][1], hr1, m1);                                       \
    float u1 = fmaf(Wp[1][0], hr0, xc.y);                                     \
    float a1 = u1 + v1;                                                       \
    float m2 = fmaf(Wp[2][2], hr2, Wp[2][3] * hr3);                           \
    float v2 = fmaf(Wp[2][1], hr1, m2);                                       \
    float u2 = fmaf(Wp[2][0], hr0, xc.z);                                     \
    float a2 = u2 + v2;                                                       \
    float m3 = fmaf(Wp[3][2], hr2, Wp[3][3] * hr3);                           \
    float v3 = fmaf(Wp[3][1], hr1, m3);                                       \
    float u3 = fmaf(Wp[3][0], hr0, xc.w);                                     \
    float a3 = u3 + v3;                                                       \
    float c0_ = __cosf(a0), c1_ = __cosf(a1), c2_ = __cosf(a2), c3_ = __cosf(a3); \
    float tt = c2_ * c3_;                                                     \
    float q1 = c0_ * c1_;                                                     \
    float q0 = c1_ * tt;                                                      \
    float q2 = q1 * c2_;                                                      \
    float q3 = q1 * tt;                                                       \
    float A0 = GACT(q0);                                                      \
    float A1 = GACT(q1);                                                      \
    float A2 = GACT(q2);                                                      \
    float A3 = GACT(q3);                                                      \
    float r1 = DPP_XOR1(sel4f(A0, A1, A2, A3, !bb0,  bb1));                   \
    float r2 = DPP_XOR2(sel4f(A0, A1, A2, A3,  bb0, !bb1));                   \
    float r3 = DPP_XOR3(sel4f(A0, A1, A2, A3, !bb0, !bb1));                   \
    float r0 = sel4f(A0, A1, A2, A3, bb0, bb1);                               \
    float fv = sel4f(r0, r1, r2, r3,  bb0,  bb1);                             \
    float iv = sel4f(r0, r1, r2, r3, !bb0,  bb1);                             \
    float uv = sel4f(r0, r1, r2, r3,  bb0, !bb1);                             \
    float ov = sel4f(r0, r1, r2, r3, !bb0, !bb1);                             \
    c = fmaf(fv, c, iv * uv);                                                 \
    float hn = ov * tanh_cf(c);                                               \
    hlds[(cc << 4) + I][lane] = hn;                                           \
    hr0 = hn;                                                                 \
    hr1 = DPP_XOR1(hn);                                                       \
    hr2 = DPP_XOR2(hn);                                                       \
    hr3 = DPP_XOR3(hn);                                                       \
} while (0)

    for (int cc = 0; cc < 8; ++cc) {
        const int bsel = cc & 1;
        QS(0);  QS(1);  QS(2);  QS(3);
        QS(4);  QS(5);  QS(6);  QS(7);
        QS(8);  QS(9);  QS(10); QS(11);
        QS(12); QS(13); QS(14); QS(15);
        if (cc < 6) {
            #pragma unroll
            for (int i = 0; i < 16; ++i)
                gload_lds16(xblk + (size_t)((cc + 2) * 16 + i) * 16384,
                            &xlds[bsel][i][0]);
            asm volatile("s_waitcnt vmcnt(16)" ::: "memory");
        } else if (cc == 6) {
            asm volatile("s_waitcnt vmcnt(0)" ::: "memory");
        }
    }
#undef QS
#undef GACT

    // epilogue: dump hlds -> hs (coalesced 16B stores)
    #pragma unroll 4
    for (int j = 0; j < 32; ++j) {
        int sp = j * 4 + (lane >> 4);
        float4 v = *(const float4*)&hlds[sp][(lane & 15) * 4];
        *(float4*)(hs + (size_t)sp * 1024 + (size_t)b0 * 4 + (lane & 15) * 4) = v;
    }
}

// ---------------- Kernel 3: logits + log_softmax ----------------
__global__ __launch_bounds__(256) void k_out(
    const float* __restrict__ hs, const float* __restrict__ Wc,
    const float* __restrict__ bc, float* __restrict__ out)
{
    int gtid = blockIdx.x * 256 + threadIdx.x;
    int r = gtid >> 3;     // r = b*S + s
    int lr = gtid & 7;
    if (r >= NB * NS) return;
    int b = r >> 7, s = r & 127;
    float4 h = *(const float4*)(hs + ((size_t)s * NB + b) * 4);
    float l[4];
    #pragma unroll
    for (int k = 0; k < 4; ++k) {
        int t = lr * 4 + k;
        float4 w = *(const float4*)(Wc + t * 4);
        l[k] = bc[t] + w.x * h.x + w.y * h.y + w.z * h.z + w.w * h.w;
    }
    float m = fmaxf(fmaxf(l[0], l[1]), fmaxf(l[2], l[3]));
    #pragma unroll
    for (int msk = 1; msk < 8; msk <<= 1)
        m = fmaxf(m, __shfl_xor(m, msk, 64));
    float sum = 0.f;
    #pragma unroll
    for (int k = 0; k < 4; ++k)
        sum += __expf(l[k] - m);
    #pragma unroll
    for (int msk = 1; msk < 8; msk <<= 1)
        sum += __shfl_xor(sum, msk, 64);
    float lse = __logf(sum);
    float4 o;
    o.x = l[0] - m - lse;
    o.y = l[1] - m - lse;
    o.z = l[2] - m - lse;
    o.w = l[3] - m - lse;
    *(float4*)(out + (size_t)r * 32 + lr * 4) = o;
}

extern "C" void kernel_launch(void* const* d_in, const int* in_sizes, int n_in,
                              void* d_out, int out_size, void* d_ws, size_t ws_size,
                              hipStream_t stream) {
    const int*   x   = (const int*)d_in[0];
    const float* emb = (const float*)d_in[1];
    const float* Wf  = (const float*)d_in[2];
    const float* bf  = (const float*)d_in[3];
    const float* Wi  = (const float*)d_in[4];
    const float* bi  = (const float*)d_in[5];
    const float* Wu  = (const float*)d_in[6];
    const float* bu  = (const float*)d_in[7];
    const float* Wo  = (const float*)d_in[8];
    const float* bo  = (const float*)d_in[9];
    const float* thf = (const float*)d_in[10];
    const float* thi = (const float*)d_in[11];
    const float* thu = (const float*)d_in[12];
    const float* tho = (const float*)d_in[13];
    const float* Wc  = (const float*)d_in[14];
    const float* bc  = (const float*)d_in[15];
    float* out = (float*)d_out;

    float* xpart = (float*)d_ws;                    // [S][B][16]  2 MB
    float* hs    = xpart + (size_t)NS * NB * 16;    // [S][B][4]   512 KB

    k_embed<<<512, 256, 0, stream>>>(x, emb, Wf, bf, Wi, bi, Wu, bu, Wo, bo,
                                     thf, thi, thu, tho, xpart);
    k_recur<<<16, 64, 0, stream>>>(Wf, Wi, Wu, Wo, xpart, hs);
    k_out<<<1024, 256, 0, stream>>>(hs, Wc, bc, out);
}

// Round 6
// 45.040 us; speedup vs baseline: 1.2538x; 1.0628x over previous
//
#include <hip/hip_runtime.h>
#include <math.h>

constexpr int NB = 256;   // batch
constexpr int NS = 128;   // seq len
constexpr int NE = 256;   // embed dim
constexpr int DIN = 260;  // E + H

typedef float f2 __attribute__((ext_vector_type(2)));
#define fma2(A, B, C) __builtin_elementwise_fma((A), (B), (C))

constexpr float INV2PI = 0.15915494309189535f;

// ---------- fast primitives ----------
__device__ __forceinline__ float rcp_fast(float x) {
#if __has_builtin(__builtin_amdgcn_rcpf)
    return __builtin_amdgcn_rcpf(x);
#else
    return 1.0f / x;
#endif
}

// cos of (x revolutions): v_fract + v_cos, no libm reduction code.
__device__ __forceinline__ float cos_rev(float x) {
    float f, r;
    asm("v_fract_f32 %0, %1" : "=v"(f) : "v"(x));
    asm("v_cos_f32 %0, %1" : "=v"(r) : "v"(f));
    return r;
}

#if __has_builtin(__builtin_amdgcn_mov_dpp)
#define DPP_XOR1(x) __int_as_float(__builtin_amdgcn_mov_dpp(__float_as_int(x), 0xB1, 0xF, 0xF, true))
#define DPP_XOR2(x) __int_as_float(__builtin_amdgcn_mov_dpp(__float_as_int(x), 0x4E, 0xF, 0xF, true))
#define DPP_XOR3(x) __int_as_float(__builtin_amdgcn_mov_dpp(__float_as_int(x), 0x1B, 0xF, 0xF, true))
#else
#define DPP_XOR1(x) __shfl_xor((x), 1, 64)
#define DPP_XOR2(x) __shfl_xor((x), 2, 64)
#define DPP_XOR3(x) __shfl_xor((x), 3, 64)
#endif

// Lambert continued-fraction tanh for the c-gate (|c| <= ~2.1): err ~2e-5.
__device__ __forceinline__ float tanh_cf(float y) {
    float w = y * y;
    float num = y * fmaf(fmaf(21.0f, w, 1260.0f), w, 10395.0f);
    float den = fmaf(fmaf(w + 210.0f, w, 4725.0f), w, 10395.0f);
    return num * rcp_fast(den);
}

__device__ __forceinline__ float sel4f(float v0, float v1, float v2, float v3,
                                       bool bit0, bool bit1) {
    float lo = bit0 ? v1 : v0;
    float hi = bit0 ? v3 : v2;
    return bit1 ? hi : lo;
}

// async global->LDS, 16B per lane. dst must be wave-uniform base; HW adds lane*16.
__device__ __forceinline__ void gload_lds16(const void* gsrc, void* ldst) {
    __builtin_amdgcn_global_load_lds(
        (const __attribute__((address_space(1))) void*)gsrc,
        (__attribute__((address_space(3))) void*)ldst, 16, 0, 0);
}

// ---------------- Kernel 1: x-part of all 4 gate preactivations ----------------
// Output is PRE-SCALED by 1/(2*pi): xpart' = (emb@W.T + b + theta) / 2pi
// 6-deep static gather prefetch: 6 outstanding 1KB emb-row gathers per wave.
__global__ __launch_bounds__(256) void k_embed(
    const int* __restrict__ x, const float* __restrict__ emb,
    const float* __restrict__ Wf, const float* __restrict__ bf,
    const float* __restrict__ Wi, const float* __restrict__ bi,
    const float* __restrict__ Wu, const float* __restrict__ bu,
    const float* __restrict__ Wo, const float* __restrict__ bo,
    const float* __restrict__ thf, const float* __restrict__ thi,
    const float* __restrict__ thu, const float* __restrict__ tho,
    float* __restrict__ xpart)
{
    const int lane = threadIdx.x & 63;
    const int wave_id = blockIdx.x * 4 + (threadIdx.x >> 6);  // 0..2047

    float4 Wreg[16];
    #pragma unroll
    for (int j = 0; j < 16; ++j) {
        const float* Wgp = (j < 8) ? ((j < 4) ? Wf : Wi) : ((j < 12) ? Wu : Wo);
        float4 w = *(const float4*)(Wgp + (j & 3) * DIN + lane * 4);
        Wreg[j] = make_float4(w.x * INV2PI, w.y * INV2PI, w.z * INV2PI, w.w * INV2PI);
    }
    float biasv;
    {
        int j = lane & 15, jj = j & 3;
        const float* bp = (j < 8) ? ((j < 4) ? bf : bi) : ((j < 12) ? bu : bo);
        const float* tp = (j < 8) ? ((j < 4) ? thf : thi) : ((j < 12) ? thu : tho);
        biasv = (bp[jj] + tp[jj]) * INV2PI;
    }

    const bool p0 = (lane & 1) != 0, p1 = (lane & 2) != 0,
               p2 = (lane & 4) != 0, p3 = (lane & 8) != 0;

    const int row0 = wave_id * 16;

#define LDE(I) (*(const float4*)(emb + \
    (size_t)x[((row0 + (I)) & 255) * NS + ((row0 + (I)) >> 8)] * NE + lane * 4))

#define PROC(I, EV) do {                                                     \
    float acc[16];                                                           \
    _Pragma("unroll")                                                        \
    for (int j = 0; j < 16; ++j) {                                           \
        float4 wv = Wreg[j];                                                 \
        acc[j] = fmaf((EV).x, wv.x, fmaf((EV).y, wv.y,                       \
                  fmaf((EV).z, wv.z, (EV).w * wv.w)));                       \
    }                                                                        \
    float t8[8];                                                             \
    _Pragma("unroll")                                                        \
    for (int i2 = 0; i2 < 8; ++i2) {                                         \
        float keep = p0 ? acc[2 * i2 + 1] : acc[2 * i2];                     \
        float send = p0 ? acc[2 * i2] : acc[2 * i2 + 1];                     \
        t8[i2] = keep + __shfl_xor(send, 1, 64);                             \
    }                                                                        \
    float t4[4];                                                             \
    _Pragma("unroll")                                                        \
    for (int i2 = 0; i2 < 4; ++i2) {                                         \
        float keep = p1 ? t8[2 * i2 + 1] : t8[2 * i2];                       \
        float send = p1 ? t8[2 * i2] : t8[2 * i2 + 1];                       \
        t4[i2] = keep + __shfl_xor(send, 2, 64);                             \
    }                                                                        \
    float t2[2];                                                             \
    _Pragma("unroll")                                                        \
    for (int i2 = 0; i2 < 2; ++i2) {                                         \
        float keep = p2 ? t4[2 * i2 + 1] : t4[2 * i2];                       \
        float send = p2 ? t4[2 * i2] : t4[2 * i2 + 1];                       \
        t2[i2] = keep + __shfl_xor(send, 4, 64);                             \
    }                                                                        \
    float keep = p3 ? t2[1] : t2[0];                                         \
    float send = p3 ? t2[0] : t2[1];                                         \
    float t1 = keep + __shfl_xor(send, 8, 64);                               \
    t1 += __shfl_xor(t1, 16, 64);                                            \
    t1 += __shfl_xor(t1, 32, 64);                                            \
    if (lane < 16)                                                           \
        xpart[(size_t)(row0 + (I)) * 16 + lane] = t1 + biasv;                \
} while (0)

    float4 ev0 = LDE(0), ev1 = LDE(1), ev2 = LDE(2),
           ev3 = LDE(3), ev4 = LDE(4), ev5 = LDE(5);
    PROC(0,  ev0); ev0 = LDE(6);
    PROC(1,  ev1); ev1 = LDE(7);
    PROC(2,  ev2); ev2 = LDE(8);
    PROC(3,  ev3); ev3 = LDE(9);
    PROC(4,  ev4); ev4 = LDE(10);
    PROC(5,  ev5); ev5 = LDE(11);
    PROC(6,  ev0); ev0 = LDE(12);
    PROC(7,  ev1); ev1 = LDE(13);
    PROC(8,  ev2); ev2 = LDE(14);
    PROC(9,  ev3); ev3 = LDE(15);
    PROC(10, ev4);
    PROC(11, ev5);
    PROC(12, ev0);
    PROC(13, ev1);
    PROC(14, ev2);
    PROC(15, ev3);
#undef PROC
#undef LDE
}

// ---------------- Kernel 2: serial LSTM recurrence, LDS-staged, vmcnt-free loop ------
// lane = gate g; 16 batches per block (1 wave). Angles tracked in REVOLUTIONS
// (inputs pre-scaled by 1/2pi) -> cos = v_fract + v_cos. Index-pairs packed as
// float2 -> v_pk_fma_f32 for the a-tree and gate polynomial.
__global__ __launch_bounds__(64) void k_recur(
    const float* __restrict__ Wf, const float* __restrict__ Wi,
    const float* __restrict__ Wu, const float* __restrict__ Wo,
    const float* __restrict__ xpart, float* __restrict__ hs)
{
    __shared__ float4 xlds[2][16][64];   // 32 KB: [buf][step-in-chunk][lane]
    __shared__ float  hlds[128][64];     // 32 KB: [s][lane]  (lane = b'*4+g)

    const int lane = threadIdx.x;
    const int g = lane & 3;
    const int b0 = blockIdx.x * 16;

    // pre-permuted recurrent weights scaled to revolutions:
    // Wp[j'][k] = W_g[j'][256 + (g^k)] / 2pi, packed as pairs (j'=0,1) and (j'=2,3)
    const float* Wg = (g == 0) ? Wf : ((g == 1) ? Wi : ((g == 2) ? Wu : Wo));
    f2 W01[4], W23[4];
    #pragma unroll
    for (int k = 0; k < 4; ++k) {
        W01[k] = f2{Wg[0 * DIN + 256 + (g ^ k)] * INV2PI,
                    Wg[1 * DIN + 256 + (g ^ k)] * INV2PI};
        W23[k] = f2{Wg[2 * DIN + 256 + (g ^ k)] * INV2PI,
                    Wg[3 * DIN + 256 + (g ^ k)] * INV2PI};
    }

    const bool bb0 = (g & 1) != 0, bb1 = (g & 2) != 0;
    // act(q) = bas + mlt * tanh(scl*q); tanh(z) ~= z*(P0+P1 w+P2 w^2+P3 w^3),
    // w=z^2, fitted on [-1,1], err <= 1e-4. mlt*scl^(2k+1) folded into coeffs.
    const float scl = (g == 2) ? 1.0f : 0.5f;
    const float mlt = (g == 2) ? 1.0f : 0.5f;
    const float bas = (g == 2) ? 0.0f : 0.5f;
    const float s2 = scl * scl;
    const float e0 = mlt * 0.999416f * scl;
    const float e1 = mlt * -0.326958f * scl * s2;
    const float e2 = mlt * 0.111796f * scl * s2 * s2;
    const float e3 = mlt * -0.022660f * scl * s2 * s2 * s2;
    const f2 D0d = {e0, e0}, D1d = {e1, e1}, D2d = {e2, e2}, D3d = {e3, e3};
    const f2 basd = {bas, bas};

    float c = 0.0f;
    float hr0 = 0.f, hr1 = 0.f, hr2 = 0.f, hr3 = 0.f;  // hr[k] = h[g^k]

    // staging source: step s occupies 1KB at xpart_bytes + s*16384 + b0*64
    const char* xblk = (const char*)xpart + (size_t)b0 * 64 + (size_t)lane * 16;

    // prologue: stage chunks 0 and 1
    #pragma unroll
    for (int i = 0; i < 16; ++i)
        gload_lds16(xblk + (size_t)i * 16384, &xlds[0][i][0]);
    #pragma unroll
    for (int i = 0; i < 16; ++i)
        gload_lds16(xblk + (size_t)(16 + i) * 16384, &xlds[1][i][0]);
    asm volatile("s_waitcnt vmcnt(16)" ::: "memory");   // chunk 0 landed

#define QS(I) do {                                                            \
    float4 xc = xlds[bsel][I][lane];                                          \
    f2 x01 = {xc.x, xc.y}, x23 = {xc.z, xc.w};                                \
    f2 h0d = {hr0, hr0}, h1d = {hr1, hr1}, h2d = {hr2, hr2}, h3d = {hr3, hr3};\
    f2 a01 = fma2(W01[0], h0d, x01);                                          \
    a01 = fma2(W01[1], h1d, a01);                                             \
    a01 = fma2(W01[2], h2d, a01);                                             \
    a01 = fma2(W01[3], h3d, a01);                                             \
    f2 a23 = fma2(W23[0], h0d, x23);                                          \
    a23 = fma2(W23[1], h1d, a23);                                             \
    a23 = fma2(W23[2], h2d, a23);                                             \
    a23 = fma2(W23[3], h3d, a23);                                             \
    float c0_ = cos_rev(a01.x), c1_ = cos_rev(a01.y);                         \
    float c2_ = cos_rev(a23.x), c3_ = cos_rev(a23.y);                         \
    float tt = c2_ * c3_;                                                     \
    float q1 = c0_ * c1_;                                                     \
    f2 q01 = {c1_ * tt, q1};                                                  \
    f2 q23 = {q1 * c2_, q1 * tt};                                             \
    f2 w01 = q01 * q01, w23 = q23 * q23;                                      \
    f2 p01 = fma2(fma2(fma2(D3d, w01, D2d), w01, D1d), w01, D0d);             \
    f2 p23 = fma2(fma2(fma2(D3d, w23, D2d), w23, D1d), w23, D0d);             \
    f2 A01 = fma2(q01, p01, basd);                                            \
    f2 A23 = fma2(q23, p23, basd);                                            \
    float A0 = A01.x, A1 = A01.y, A2 = A23.x, A3 = A23.y;                     \
    float r1 = DPP_XOR1(sel4f(A0, A1, A2, A3, !bb0,  bb1));                   \
    float r2 = DPP_XOR2(sel4f(A0, A1, A2, A3,  bb0, !bb1));                   \
    float r3 = DPP_XOR3(sel4f(A0, A1, A2, A3, !bb0, !bb1));                   \
    float r0 = sel4f(A0, A1, A2, A3, bb0, bb1);                               \
    float fv = sel4f(r0, r1, r2, r3,  bb0,  bb1);                             \
    float iv = sel4f(r0, r1, r2, r3, !bb0,  bb1);                             \
    float uv = sel4f(r0, r1, r2, r3,  bb0, !bb1);                             \
    float ov = sel4f(r0, r1, r2, r3, !bb0, !bb1);                             \
    c = fmaf(fv, c, iv * uv);                                                 \
    float hn = ov * tanh_cf(c);                                               \
    hlds[(cc << 4) + I][lane] = hn;                                           \
    hr0 = hn;                                                                 \
    hr1 = DPP_XOR1(hn);                                                       \
    hr2 = DPP_XOR2(hn);                                                       \
    hr3 = DPP_XOR3(hn);                                                       \
} while (0)

    for (int cc = 0; cc < 8; ++cc) {
        const int bsel = cc & 1;
        QS(0);  QS(1);  QS(2);  QS(3);
        QS(4);  QS(5);  QS(6);  QS(7);
        QS(8);  QS(9);  QS(10); QS(11);
        QS(12); QS(13); QS(14); QS(15);
        if (cc < 6) {
            #pragma unroll
            for (int i = 0; i < 16; ++i)
                gload_lds16(xblk + (size_t)((cc + 2) * 16 + i) * 16384,
                            &xlds[bsel][i][0]);
            asm volatile("s_waitcnt vmcnt(16)" ::: "memory");
        } else if (cc == 6) {
            asm volatile("s_waitcnt vmcnt(0)" ::: "memory");
        }
    }
#undef QS

    // epilogue: dump hlds -> hs (coalesced 16B stores)
    #pragma unroll 4
    for (int j = 0; j < 32; ++j) {
        int sp = j * 4 + (lane >> 4);
        float4 v = *(const float4*)&hlds[sp][(lane & 15) * 4];
        *(float4*)(hs + (size_t)sp * 1024 + (size_t)b0 * 4 + (lane & 15) * 4) = v;
    }
}

// ---------------- Kernel 3: logits + log_softmax ----------------
__global__ __launch_bounds__(256) void k_out(
    const float* __restrict__ hs, const float* __restrict__ Wc,
    const float* __restrict__ bc, float* __restrict__ out)
{
    int gtid = blockIdx.x * 256 + threadIdx.x;
    int r = gtid >> 3;     // r = b*S + s
    int lr = gtid & 7;
    if (r >= NB * NS) return;
    int b = r >> 7, s = r & 127;
    float4 h = *(const float4*)(hs + ((size_t)s * NB + b) * 4);
    float l[4];
    #pragma unroll
    for (int k = 0; k < 4; ++k) {
        int t = lr * 4 + k;
        float4 w = *(const float4*)(Wc + t * 4);
        l[k] = bc[t] + w.x * h.x + w.y * h.y + w.z * h.z + w.w * h.w;
    }
    float m = fmaxf(fmaxf(l[0], l[1]), fmaxf(l[2], l[3]));
    #pragma unroll
    for (int msk = 1; msk < 8; msk <<= 1)
        m = fmaxf(m, __shfl_xor(m, msk, 64));
    float sum = 0.f;
    #pragma unroll
    for (int k = 0; k < 4; ++k)
        sum += __expf(l[k] - m);
    #pragma unroll
    for (int msk = 1; msk < 8; msk <<= 1)
        sum += __shfl_xor(sum, msk, 64);
    float lse = __logf(sum);
    float4 o;
    o.x = l[0] - m - lse;
    o.y = l[1] - m - lse;
    o.z = l[2] - m - lse;
    o.w = l[3] - m - lse;
    *(float4*)(out + (size_t)r * 32 + lr * 4) = o;
}

extern "C" void kernel_launch(void* const* d_in, const int* in_sizes, int n_in,
                              void* d_out, int out_size, void* d_ws, size_t ws_size,
                              hipStream_t stream) {
    const int*   x   = (const int*)d_in[0];
    const float* emb = (const float*)d_in[1];
    const float* Wf  = (const float*)d_in[2];
    const float* bf  = (const float*)d_in[3];
    const float* Wi  = (const float*)d_in[4];
    const float* bi  = (const float*)d_in[5];
    const float* Wu  = (const float*)d_in[6];
    const float* bu  = (const float*)d_in[7];
    const float* Wo  = (const float*)d_in[8];
    const float* bo  = (const float*)d_in[9];
    const float* thf = (const float*)d_in[10];
    const float* thi = (const float*)d_in[11];
    const float* thu = (const float*)d_in[12];
    const float* tho = (const float*)d_in[13];
    const float* Wc  = (const float*)d_in[14];
    const float* bc  = (const float*)d_in[15];
    float* out = (float*)d_out;

    float* xpart = (float*)d_ws;                    // [S][B][16]  2 MB
    float* hs    = xpart + (size_t)NS * NB * 16;    // [S][B][4]   512 KB

    k_embed<<<512, 256, 0, stream>>>(x, emb, Wf, bf, Wi, bi, Wu, bu, Wo, bo,
                                     thf, thi, thu, tho, xpart);
    k_recur<<<16, 64, 0, stream>>>(Wf, Wi, Wu, Wo, xpart, hs);
    k_out<<<1024, 256, 0, stream>>>(hs, Wc, bc, out);
}

// Round 7
// 41.272 us; speedup vs baseline: 1.3683x; 1.0913x over previous
//
#include <hip/hip_runtime.h>
#include <math.h>

constexpr int NB = 256;   // batch
constexpr int NS = 128;   // seq len
constexpr int NE = 256;   // embed dim
constexpr int DIN = 260;  // E + H

typedef float f2 __attribute__((ext_vector_type(2)));
#define fma2(A, B, C) __builtin_elementwise_fma((A), (B), (C))

constexpr float INV2PI = 0.15915494309189535f;

// ---------- fast primitives ----------
__device__ __forceinline__ float rcp_fast(float x) {
#if __has_builtin(__builtin_amdgcn_rcpf)
    return __builtin_amdgcn_rcpf(x);
#else
    return 1.0f / x;
#endif
}

// cos of (x revolutions): v_fract + v_cos, no libm reduction code.
__device__ __forceinline__ float cos_rev(float x) {
    float f, r;
    asm("v_fract_f32 %0, %1" : "=v"(f) : "v"(x));
    asm("v_cos_f32 %0, %1" : "=v"(r) : "v"(f));
    return r;
}

#if __has_builtin(__builtin_amdgcn_mov_dpp)
#define DPP_XOR1(x) __int_as_float(__builtin_amdgcn_mov_dpp(__float_as_int(x), 0xB1, 0xF, 0xF, true))
#define DPP_XOR2(x) __int_as_float(__builtin_amdgcn_mov_dpp(__float_as_int(x), 0x4E, 0xF, 0xF, true))
#define DPP_XOR3(x) __int_as_float(__builtin_amdgcn_mov_dpp(__float_as_int(x), 0x1B, 0xF, 0xF, true))
#else
#define DPP_XOR1(x) __shfl_xor((x), 1, 64)
#define DPP_XOR2(x) __shfl_xor((x), 2, 64)
#define DPP_XOR3(x) __shfl_xor((x), 3, 64)
#endif

// Lambert continued-fraction tanh for the c-gate (|c| <= ~2.1): err ~2e-5.
__device__ __forceinline__ float tanh_cf(float y) {
    float w = y * y;
    float num = y * fmaf(fmaf(21.0f, w, 1260.0f), w, 10395.0f);
    float den = fmaf(fmaf(w + 210.0f, w, 4725.0f), w, 10395.0f);
    return num * rcp_fast(den);
}

__device__ __forceinline__ float sel4f(float v0, float v1, float v2, float v3,
                                       bool bit0, bool bit1) {
    float lo = bit0 ? v1 : v0;
    float hi = bit0 ? v3 : v2;
    return bit1 ? hi : lo;
}

// ---------------- Kernel 1: x-part of all 4 gate preactivations ----------------
// Output is PRE-SCALED by 1/(2*pi): xpart' = (emb@W.T + b + theta) / 2pi
// 6-deep static gather prefetch: 6 outstanding 1KB emb-row gathers per wave.
__global__ __launch_bounds__(256) void k_embed(
    const int* __restrict__ x, const float* __restrict__ emb,
    const float* __restrict__ Wf, const float* __restrict__ bf,
    const float* __restrict__ Wi, const float* __restrict__ bi,
    const float* __restrict__ Wu, const float* __restrict__ bu,
    const float* __restrict__ Wo, const float* __restrict__ bo,
    const float* __restrict__ thf, const float* __restrict__ thi,
    const float* __restrict__ thu, const float* __restrict__ tho,
    float* __restrict__ xpart)
{
    const int lane = threadIdx.x & 63;
    const int wave_id = blockIdx.x * 4 + (threadIdx.x >> 6);  // 0..2047

    float4 Wreg[16];
    #pragma unroll
    for (int j = 0; j < 16; ++j) {
        const float* Wgp = (j < 8) ? ((j < 4) ? Wf : Wi) : ((j < 12) ? Wu : Wo);
        float4 w = *(const float4*)(Wgp + (j & 3) * DIN + lane * 4);
        Wreg[j] = make_float4(w.x * INV2PI, w.y * INV2PI, w.z * INV2PI, w.w * INV2PI);
    }
    float biasv;
    {
        int j = lane & 15, jj = j & 3;
        const float* bp = (j < 8) ? ((j < 4) ? bf : bi) : ((j < 12) ? bu : bo);
        const float* tp = (j < 8) ? ((j < 4) ? thf : thi) : ((j < 12) ? thu : tho);
        biasv = (bp[jj] + tp[jj]) * INV2PI;
    }

    const bool p0 = (lane & 1) != 0, p1 = (lane & 2) != 0,
               p2 = (lane & 4) != 0, p3 = (lane & 8) != 0;

    const int row0 = wave_id * 16;

#define LDE(I) (*(const float4*)(emb + \
    (size_t)x[((row0 + (I)) & 255) * NS + ((row0 + (I)) >> 8)] * NE + lane * 4))

#define PROC(I, EV) do {                                                     \
    float acc[16];                                                           \
    _Pragma("unroll")                                                        \
    for (int j = 0; j < 16; ++j) {                                           \
        float4 wv = Wreg[j];                                                 \
        acc[j] = fmaf((EV).x, wv.x, fmaf((EV).y, wv.y,                       \
                  fmaf((EV).z, wv.z, (EV).w * wv.w)));                       \
    }                                                                        \
    float t8[8];                                                             \
    _Pragma("unroll")                                                        \
    for (int i2 = 0; i2 < 8; ++i2) {                                         \
        float keep = p0 ? acc[2 * i2 + 1] : acc[2 * i2];                     \
        float send = p0 ? acc[2 * i2] : acc[2 * i2 + 1];                     \
        t8[i2] = keep + __shfl_xor(send, 1, 64);                             \
    }                                                                        \
    float t4[4];                                                             \
    _Pragma("unroll")                                                        \
    for (int i2 = 0; i2 < 4; ++i2) {                                         \
        float keep = p1 ? t8[2 * i2 + 1] : t8[2 * i2];                       \
        float send = p1 ? t8[2 * i2] : t8[2 * i2 + 1];                       \
        t4[i2] = keep + __shfl_xor(send, 2, 64);                             \
    }                                                                        \
    float t2[2];                                                             \
    _Pragma("unroll")                                                        \
    for (int i2 = 0; i2 < 2; ++i2) {                                         \
        float keep = p2 ? t4[2 * i2 + 1] : t4[2 * i2];                       \
        float send = p2 ? t4[2 * i2] : t4[2 * i2 + 1];                       \
        t2[i2] = keep + __shfl_xor(send, 4, 64);                             \
    }                                                                        \
    float keep = p3 ? t2[1] : t2[0];                                         \
    float send = p3 ? t2[0] : t2[1];                                         \
    float t1 = keep + __shfl_xor(send, 8, 64);                               \
    t1 += __shfl_xor(t1, 16, 64);                                            \
    t1 += __shfl_xor(t1, 32, 64);                                            \
    if (lane < 16)                                                           \
        xpart[(size_t)(row0 + (I)) * 16 + lane] = t1 + biasv;                \
} while (0)

    float4 ev0 = LDE(0), ev1 = LDE(1), ev2 = LDE(2),
           ev3 = LDE(3), ev4 = LDE(4), ev5 = LDE(5);
    PROC(0,  ev0); ev0 = LDE(6);
    PROC(1,  ev1); ev1 = LDE(7);
    PROC(2,  ev2); ev2 = LDE(8);
    PROC(3,  ev3); ev3 = LDE(9);
    PROC(4,  ev4); ev4 = LDE(10);
    PROC(5,  ev5); ev5 = LDE(11);
    PROC(6,  ev0); ev0 = LDE(12);
    PROC(7,  ev1); ev1 = LDE(13);
    PROC(8,  ev2); ev2 = LDE(14);
    PROC(9,  ev3); ev3 = LDE(15);
    PROC(10, ev4);
    PROC(11, ev5);
    PROC(12, ev0);
    PROC(13, ev1);
    PROC(14, ev2);
    PROC(15, ev3);
#undef PROC
#undef LDE
}

// ---------------- Kernel 2: serial LSTM recurrence ----------------
// lane = gate g; 16 batches per block (1 wave). Angles in REVOLUTIONS
// (inputs pre-scaled by 1/2pi) -> cos = v_fract + v_cos. Packed pairs ->
// v_pk_fma_f32. xpart feed: named-register prefetch ring (2 chunks x 8
// float4), prefetch distance 16 steps (~4000 cy >> HBM ~900 cy); the vmcnt
// FIFO holds ONLY these loads. hn stores go to LDS (lgkmcnt, fire-and-forget),
// bulk-dumped to global in the epilogue.
__global__ __launch_bounds__(64) void k_recur(
    const float* __restrict__ Wf, const float* __restrict__ Wi,
    const float* __restrict__ Wu, const float* __restrict__ Wo,
    const float* __restrict__ xpart, float* __restrict__ hs)
{
    __shared__ float hlds[128][64];     // 32 KB: [s][lane]  (lane = b'*4+g)

    const int lane = threadIdx.x;
    const int g = lane & 3;
    const int b0 = blockIdx.x * 16;

    // pre-permuted recurrent weights scaled to revolutions:
    // Wp[j'][k] = W_g[j'][256 + (g^k)] / 2pi, packed (j'=0,1) and (j'=2,3)
    const float* Wg = (g == 0) ? Wf : ((g == 1) ? Wi : ((g == 2) ? Wu : Wo));
    f2 W01[4], W23[4];
    #pragma unroll
    for (int k = 0; k < 4; ++k) {
        W01[k] = f2{Wg[0 * DIN + 256 + (g ^ k)] * INV2PI,
                    Wg[1 * DIN + 256 + (g ^ k)] * INV2PI};
        W23[k] = f2{Wg[2 * DIN + 256 + (g ^ k)] * INV2PI,
                    Wg[3 * DIN + 256 + (g ^ k)] * INV2PI};
    }

    const bool bb0 = (g & 1) != 0, bb1 = (g & 2) != 0;
    // act(q) = bas + mlt * tanh(scl*q); tanh(z) ~= z*(P0+P1 w+P2 w^2+P3 w^3),
    // w=z^2, fitted on [-1,1], err <= 1e-4. mlt*scl^(2k+1) folded into coeffs.
    const float scl = (g == 2) ? 1.0f : 0.5f;
    const float mlt = (g == 2) ? 1.0f : 0.5f;
    const float bas = (g == 2) ? 0.0f : 0.5f;
    const float s2 = scl * scl;
    const float e0 = mlt * 0.999416f * scl;
    const float e1 = mlt * -0.326958f * scl * s2;
    const float e2 = mlt * 0.111796f * scl * s2 * s2;
    const float e3 = mlt * -0.022660f * scl * s2 * s2 * s2;
    const f2 D0d = {e0, e0}, D1d = {e1, e1}, D2d = {e2, e2}, D3d = {e3, e3};
    const f2 basd = {bas, bas};

    float c = 0.0f;
    float hr0 = 0.f, hr1 = 0.f, hr2 = 0.f, hr3 = 0.f;  // hr[k] = h[g^k]

    // per-lane source: step s -> xpart_bytes + s*16384 + b0*64 + lane*16
    const char* xblk = (const char*)xpart + (size_t)b0 * 64 + (size_t)lane * 16;

#define LDX(CH, K) (*(const float4*)(xblk + (size_t)(((CH) * 8 + (K)) * 16384)))

#define QS(XC, S) do {                                                        \
    f2 x01 = {(XC).x, (XC).y}, x23 = {(XC).z, (XC).w};                        \
    f2 h0d = {hr0, hr0}, h1d = {hr1, hr1}, h2d = {hr2, hr2}, h3d = {hr3, hr3};\
    f2 a01 = fma2(W01[0], h0d, x01);                                          \
    f2 n01 = W01[2] * h2d;                                                    \
    a01 = fma2(W01[1], h1d, a01);                                             \
    n01 = fma2(W01[3], h3d, n01);                                             \
    a01 = a01 + n01;                                                          \
    f2 a23 = fma2(W23[0], h0d, x23);                                          \
    f2 n23 = W23[2] * h2d;                                                    \
    a23 = fma2(W23[1], h1d, a23);                                             \
    n23 = fma2(W23[3], h3d, n23);                                             \
    a23 = a23 + n23;                                                          \
    float c0_ = cos_rev(a01.x), c1_ = cos_rev(a01.y);                         \
    float c2_ = cos_rev(a23.x), c3_ = cos_rev(a23.y);                         \
    float tt = c2_ * c3_;                                                     \
    float q1 = c0_ * c1_;                                                     \
    f2 q01 = {c1_ * tt, q1};                                                  \
    f2 q23 = {q1 * c2_, q1 * tt};                                             \
    f2 w01 = q01 * q01, w23 = q23 * q23;                                      \
    f2 p01 = fma2(fma2(fma2(D3d, w01, D2d), w01, D1d), w01, D0d);             \
    f2 p23 = fma2(fma2(fma2(D3d, w23, D2d), w23, D1d), w23, D0d);             \
    f2 A01 = fma2(q01, p01, basd);                                            \
    f2 A23 = fma2(q23, p23, basd);                                            \
    float A0 = A01.x, A1 = A01.y, A2 = A23.x, A3 = A23.y;                     \
    float r1 = DPP_XOR1(sel4f(A0, A1, A2, A3, !bb0,  bb1));                   \
    float r2 = DPP_XOR2(sel4f(A0, A1, A2, A3,  bb0, !bb1));                   \
    float r3 = DPP_XOR3(sel4f(A0, A1, A2, A3, !bb0, !bb1));                   \
    float r0 = sel4f(A0, A1, A2, A3, bb0, bb1);                               \
    float fv = sel4f(r0, r1, r2, r3,  bb0,  bb1);                             \
    float iv = sel4f(r0, r1, r2, r3, !bb0,  bb1);                             \
    float uv = sel4f(r0, r1, r2, r3,  bb0, !bb1);                             \
    float ov = sel4f(r0, r1, r2, r3, !bb0, !bb1);                             \
    c = fmaf(fv, c, iv * uv);                                                 \
    float hn = ov * tanh_cf(c);                                               \
    hlds[S][lane] = hn;                                                       \
    hr0 = hn;                                                                 \
    hr1 = DPP_XOR1(hn);                                                       \
    hr2 = DPP_XOR2(hn);                                                       \
    hr3 = DPP_XOR3(hn);                                                       \
} while (0)

    // preload chunks 0 and 1 (16 steps)
    float4 xA0 = LDX(0, 0), xA1 = LDX(0, 1), xA2 = LDX(0, 2), xA3 = LDX(0, 3);
    float4 xA4 = LDX(0, 4), xA5 = LDX(0, 5), xA6 = LDX(0, 6), xA7 = LDX(0, 7);
    float4 xB0 = LDX(1, 0), xB1 = LDX(1, 1), xB2 = LDX(1, 2), xB3 = LDX(1, 3);
    float4 xB4 = LDX(1, 4), xB5 = LDX(1, 5), xB6 = LDX(1, 6), xB7 = LDX(1, 7);

    for (int cp = 0; cp < 8; ++cp) {
        int s0 = cp * 16;
        int chA = (cp * 2 + 2) & 15;   // cp==7 wraps: redundant L2-hit reload, branch-free
        int chB = (cp * 2 + 3) & 15;
        QS(xA0, s0 + 0);  xA0 = LDX(chA, 0);
        QS(xA1, s0 + 1);  xA1 = LDX(chA, 1);
        QS(xA2, s0 + 2);  xA2 = LDX(chA, 2);
        QS(xA3, s0 + 3);  xA3 = LDX(chA, 3);
        QS(xA4, s0 + 4);  xA4 = LDX(chA, 4);
        QS(xA5, s0 + 5);  xA5 = LDX(chA, 5);
        QS(xA6, s0 + 6);  xA6 = LDX(chA, 6);
        QS(xA7, s0 + 7);  xA7 = LDX(chA, 7);
        QS(xB0, s0 + 8);  xB0 = LDX(chB, 0);
        QS(xB1, s0 + 9);  xB1 = LDX(chB, 1);
        QS(xB2, s0 + 10); xB2 = LDX(chB, 2);
        QS(xB3, s0 + 11); xB3 = LDX(chB, 3);
        QS(xB4, s0 + 12); xB4 = LDX(chB, 4);
        QS(xB5, s0 + 13); xB5 = LDX(chB, 5);
        QS(xB6, s0 + 14); xB6 = LDX(chB, 6);
        QS(xB7, s0 + 15); xB7 = LDX(chB, 7);
    }
#undef QS
#undef LDX

    // epilogue: dump hlds -> hs (coalesced 16B stores)
    __builtin_amdgcn_s_waitcnt(0);   // drain lgkm (ds_writes) before re-reading
    #pragma unroll 4
    for (int j = 0; j < 32; ++j) {
        int sp = j * 4 + (lane >> 4);
        float4 v = *(const float4*)&hlds[sp][(lane & 15) * 4];
        *(float4*)(hs + (size_t)sp * 1024 + (size_t)b0 * 4 + (lane & 15) * 4) = v;
    }
}

// ---------------- Kernel 3: logits + log_softmax ----------------
__global__ __launch_bounds__(256) void k_out(
    const float* __restrict__ hs, const float* __restrict__ Wc,
    const float* __restrict__ bc, float* __restrict__ out)
{
    int gtid = blockIdx.x * 256 + threadIdx.x;
    int r = gtid >> 3;     // r = b*S + s
    int lr = gtid & 7;
    if (r >= NB * NS) return;
    int b = r >> 7, s = r & 127;
    float4 h = *(const float4*)(hs + ((size_t)s * NB + b) * 4);
    float l[4];
    #pragma unroll
    for (int k = 0; k < 4; ++k) {
        int t = lr * 4 + k;
        float4 w = *(const float4*)(Wc + t * 4);
        l[k] = bc[t] + w.x * h.x + w.y * h.y + w.z * h.z + w.w * h.w;
    }
    float m = fmaxf(fmaxf(l[0], l[1]), fmaxf(l[2], l[3]));
    #pragma unroll
    for (int msk = 1; msk < 8; msk <<= 1)
        m = fmaxf(m, __shfl_xor(m, msk, 64));
    float sum = 0.f;
    #pragma unroll
    for (int k = 0; k < 4; ++k)
        sum += __expf(l[k] - m);
    #pragma unroll
    for (int msk = 1; msk < 8; msk <<= 1)
        sum += __shfl_xor(sum, msk, 64);
    float lse = __logf(sum);
    float4 o;
    o.x = l[0] - m - lse;
    o.y = l[1] - m - lse;
    o.z = l[2] - m - lse;
    o.w = l[3] - m - lse;
    *(float4*)(out + (size_t)r * 32 + lr * 4) = o;
}

extern "C" void kernel_launch(void* const* d_in, const int* in_sizes, int n_in,
                              void* d_out, int out_size, void* d_ws, size_t ws_size,
                              hipStream_t stream) {
    const int*   x   = (const int*)d_in[0];
    const float* emb = (const float*)d_in[1];
    const float* Wf  = (const float*)d_in[2];
    const float* bf  = (const float*)d_in[3];
    const float* Wi  = (const float*)d_in[4];
    const float* bi  = (const float*)d_in[5];
    const float* Wu  = (const float*)d_in[6];
    const float* bu  = (const float*)d_in[7];
    const float* Wo  = (const float*)d_in[8];
    const float* bo  = (const float*)d_in[9];
    const float* thf = (const float*)d_in[10];
    const float* thi = (const float*)d_in[11];
    const float* thu = (const float*)d_in[12];
    const float* tho = (const float*)d_in[13];
    const float* Wc  = (const float*)d_in[14];
    const float* bc  = (const float*)d_in[15];
    float* out = (float*)d_out;

    float* xpart = (float*)d_ws;                    // [S][B][16]  2 MB
    float* hs    = xpart + (size_t)NS * NB * 16;    // [S][B][4]   512 KB

    k_embed<<<512, 256, 0, stream>>>(x, emb, Wf, bf, Wi, bi, Wu, bu, Wo, bo,
                                     thf, thi, thu, tho, xpart);
    k_recur<<<16, 64, 0, stream>>>(Wf, Wi, Wu, Wo, xpart, hs);
    k_out<<<1024, 256, 0, stream>>>(hs, Wc, bc, out);
}